// Round 11
// baseline (56.145 us; speedup 1.0000x reference)
//
#include <hip/hip_runtime.h>

// ContrastiveLoss on MI355X — symmetric Gram, ROW-SPLIT half-tiles for
// occupancy. r9 diagnostic: BK=32 2-barrier body at 528 blocks = 2.06
// blocks/CU is latency-bound (MfmaUtil 20%, 77% stall, nothing to overlap).
// Split each 128x128 tile into two 64x128 row-half blocks -> grid 1056
// (4.1 blocks/CU), LDS 12KB, acc 2x4 (VGPR ~80). Row-side reductions stay
// complete in-block; col-side become 64-row partials -- the atomics already
// accumulate partials correctly. Swizzle = r5-verified pair (rule #21):
// source chunk (t&3)^((t>>3)&3), read chunk fh^((fr>>1)&3) -> 2-way = free.

#define KGRP 8
#define FD   512
#define N1T  2048
#define NT   4096
#define TEMPW 0.02f

typedef __attribute__((ext_vector_type(8))) short short8;
typedef __attribute__((ext_vector_type(4))) float f32x4;
typedef unsigned short ushort_t;

// ---- helpers ---------------------------------------------------------------

__device__ __forceinline__ unsigned enc_ord(float f) {
  unsigned u = __float_as_uint(f);
  return (u & 0x80000000u) ? ~u : (u | 0x80000000u);
}
__device__ __forceinline__ float dec_ord(unsigned u) {
  unsigned b = (u & 0x80000000u) ? (u & 0x7fffffffu) : ~u;
  return __uint_as_float(b);
}

__device__ __forceinline__ ushort_t f2bf(float f) {
  unsigned u = __float_as_uint(f);
  u = (u + 0x7fffu + ((u >> 16) & 1u)) >> 16;
  return (ushort_t)u;
}

__device__ __forceinline__ void gld16(const void* g, void* l) {
  __builtin_amdgcn_global_load_lds(
      (const __attribute__((address_space(1))) unsigned*)g,
      (__attribute__((address_space(3))) unsigned*)l, 16, 0, 0);
}

// cnts layout: [0]=nn [1]=np [2]=pos done counter

// ---- prep: bf16 convert + zero accumulators + class table + tile lists -----
__global__ __launch_bounds__(256) void prep_k(
    const float* __restrict__ f1, const float* __restrict__ f2,
    ushort_t* __restrict__ bf,
    float* __restrict__ neg_sum, unsigned* __restrict__ neg_max,
    float* __restrict__ sumS, float* __restrict__ corr,
    int* __restrict__ cnts, int* __restrict__ neg_list,
    int* __restrict__ pos_list, const int* __restrict__ ov)
{
  const int b = blockIdx.x, t = threadIdx.x;

  {
    int i = b * 256 + t;
    size_t base = (size_t)i * 8;
    const size_t half = (size_t)N1T * FD;
    const float* sp = (base < half) ? (f1 + base) : (f2 + (base - half));
    float4 u0 = ((const float4*)sp)[0];
    float4 u1 = ((const float4*)sp)[1];
    short8 o;
    o[0] = (short)f2bf(u0.x); o[1] = (short)f2bf(u0.y);
    o[2] = (short)f2bf(u0.z); o[3] = (short)f2bf(u0.w);
    o[4] = (short)f2bf(u1.x); o[5] = (short)f2bf(u1.y);
    o[6] = (short)f2bf(u1.z); o[7] = (short)f2bf(u1.w);
    *(short8*)(bf + base) = o;
  }

  if (b >= 1 && b <= 16) {
    int i = (b - 1) * 256 + t;
    neg_sum[i] = 0.f;
    neg_max[i] = 0u;                    // 0u < enc_ord(any float)
  }

  if (b == 0) {
    __shared__ int c[16];
    if (t == 0) {
      sumS[0] = 0.f; corr[0] = 0.f;
      cnts[0] = 0; cnts[1] = 0; cnts[2] = 0;
      int excl = 0;
      for (int g = 0; g < KGRP; g++) c[g] = g;
      for (int g = 0; g < KGRP; g++) {
        if (ov[g]) c[KGRP + g] = g;
        else       { c[KGRP + g] = KGRP + excl; excl++; }
      }
    }
    __syncthreads();
    for (int p = t; p < 1024; p += 256) {
      int bi = p >> 5, bj = p & 31;
      if (bj < bi) continue;
      if (c[bi >> 1] == c[bj >> 1]) {
        int k = atomicAdd(&cnts[1], 1); pos_list[k] = (bi << 5) | bj;
      } else {
        int k = atomicAdd(&cnts[0], 1); neg_list[k] = (bi << 5) | bj;
      }
    }
  }
}

// ---- gram pass: 1056 half-tile blocks (64 rows x 128 cols each) ------------
__global__ __launch_bounds__(256) void gram_k(
    const ushort_t* __restrict__ bf, const int* __restrict__ cnts,
    const int* __restrict__ neg_list, const int* __restrict__ pos_list,
    float* __restrict__ neg_sum, unsigned* __restrict__ neg_max,
    float* __restrict__ pos_dots)
{
  __shared__ char lds[12288];           // A[64][32] 4KB | B[128][32] 8KB

  const int nn = cnts[0];
  const int b  = blockIdx.x;
  const bool isneg = (b < 2 * nn);
  int tile, h;
  if (isneg) { tile = neg_list[b >> 1]; h = b & 1; }
  else       { int q = b - 2 * nn; tile = pos_list[q >> 1]; h = q & 1; }
  const int bi = tile >> 5, bj = tile & 31;
  const int arow = (bi << 7) + (h << 6);   // this block's 64 A-rows
  const int bcol = bj << 7;                // full 128 B-cols

  const int t    = threadIdx.x;
  const int lane = t & 63, wave = t >> 6;
  const int wr   = (wave >> 1) << 5;    // A row group within half: 0 / 32
  const int wc   = (wave & 1) << 6;     // col group: 0 / 64
  const int fr   = lane & 15, fh = lane >> 4;

  // staging: wave w covers 16 rows (lane>>2), chunk (lane&3) XOR-swizzled
  const int srow   = lane >> 2;
  const int schunk = ((lane & 3) ^ ((lane >> 3) & 3)) << 3;   // elems
  const ushort_t* gA = bf + (size_t)(arow + (wave << 4) + srow) * FD + schunk;
  const ushort_t* gB = bf + (size_t)(bcol + (wave << 4) + srow) * FD + schunk;
  char* const dA = lds + (wave << 10);              // + lane*16 implicit
  char* const dB = lds + 4096 + (wave << 10);       // + j*4096

  // fragment read offsets: row*64 + (fh ^ ((fr>>1)&3))*16
  const int cx = (fh ^ ((fr >> 1) & 3)) << 4;
  int offA[2], offB[4];
#pragma unroll
  for (int m = 0; m < 2; m++) offA[m] = ((wr + (m << 4) + fr) << 6) + cx;
#pragma unroll
  for (int n = 0; n < 4; n++) offB[n] = 4096 + ((wc + (n << 4) + fr) << 6) + cx;

  f32x4 acc[2][4];
#pragma unroll
  for (int m = 0; m < 2; m++)
#pragma unroll
    for (int n = 0; n < 4; n++)
      acc[m][n] = (f32x4){0.f, 0.f, 0.f, 0.f};

  for (int s = 0; s < 16; s++) {        // 16 K-steps of 32
    gld16(gA + (s << 5),                   dA);
    gld16(gB + (s << 5),                   dB);
    gld16(gB + (size_t)64 * FD + (s << 5), dB + 4096);
    __syncthreads();                    // drains vmcnt, then barrier

    short8 a[2], bb[4];
#pragma unroll
    for (int m = 0; m < 2; m++) a[m]  = *(const short8*)(lds + offA[m]);
#pragma unroll
    for (int n = 0; n < 4; n++) bb[n] = *(const short8*)(lds + offB[n]);

#pragma unroll
    for (int m = 0; m < 2; m++)
#pragma unroll
      for (int n = 0; n < 4; n++)
        acc[m][n] = __builtin_amdgcn_mfma_f32_16x16x32_bf16(a[m], bb[n], acc[m][n], 0, 0, 0);
    __syncthreads();                    // WAR: reads done before next stage
  }

  const int rbase = arow + wr + (fh << 2);   // + m*16 + j
  const int cbase = bcol + wc + fr;          // + n*16

  if (isneg) {
    // row-side (complete: all 128 cols split across 2 wc-waves) and
    // col-side (partial: this block's 64 rows) exp-sums/maxes in one sweep
    float colS[4] = {0.f, 0.f, 0.f, 0.f};
    float colM[4] = {-3.0e38f, -3.0e38f, -3.0e38f, -3.0e38f};
#pragma unroll
    for (int m = 0; m < 2; m++) {
#pragma unroll
      for (int j = 0; j < 4; j++) {
        float s = 0.f, mx = -3.0e38f;
#pragma unroll
        for (int n = 0; n < 4; n++) {
          float d = acc[m][n][j];
          float e = __expf(d * TEMPW);
          s += e; mx = fmaxf(mx, d);
          colS[n] += e; colM[n] = fmaxf(colM[n], d);
        }
#pragma unroll
        for (int o = 1; o < 16; o <<= 1) {
          s  += __shfl_xor(s, o, 64);
          mx  = fmaxf(mx, __shfl_xor(mx, o, 64));
        }
        if (fr == 0) {
          int r = rbase + (m << 4) + j;
          atomicAdd(&neg_sum[r], s);
          atomicMax(&neg_max[r], enc_ord(mx));
        }
      }
    }
#pragma unroll
    for (int n = 0; n < 4; n++) {
      float s = colS[n], mx = colM[n];
      s += __shfl_xor(s, 16, 64); mx = fmaxf(mx, __shfl_xor(mx, 16, 64));
      s += __shfl_xor(s, 32, 64); mx = fmaxf(mx, __shfl_xor(mx, 32, 64));
      if (fh == 0) {
        int c = cbase + (n << 4);
        atomicAdd(&neg_sum[c], s);
        atomicMax(&neg_max[c], enc_ord(mx));
      }
    }
  } else {
    // pos half-tile: dump 64x128 dots to scratch
    float* basep = pos_dots + (size_t)(b - 2 * nn) * 8192;
#pragma unroll
    for (int m = 0; m < 2; m++)
#pragma unroll
      for (int n = 0; n < 4; n++)
        *(f32x4*)(basep + (((m << 2) + n) << 10) + (t << 2)) = acc[m][n];
  }
}

// ---- fused pos-compare + finalize (last pos half-block runs finalize) ------
__global__ __launch_bounds__(256) void pos_fin_k(
    const float* __restrict__ pos_dots, const int* __restrict__ cnts,
    const int* __restrict__ pos_list, const unsigned* __restrict__ neg_max,
    const float* __restrict__ neg_sum, const int* __restrict__ ov,
    float* __restrict__ sumS, float* __restrict__ corr,
    int* __restrict__ done, float* __restrict__ out)
{
  const int np2 = 2 * cnts[1];
  const int p   = blockIdx.x;
  const int t   = threadIdx.x, lane = t & 63, wave = t >> 6;

  __shared__ float wsum[4];
  __shared__ int   wcnt[4];
  __shared__ int   amLast;

  if (p < np2) {
    const int tile = pos_list[p >> 1];
    const int h    = p & 1;
    const int bi = tile >> 5, bj = tile & 31;
    const int wr = (wave >> 1) << 5, wc = (wave & 1) << 6;
    const int fr = lane & 15, fh = lane >> 4;
    const int rbase = (bi << 7) + (h << 6) + wr + (fh << 2);  // + m*16 + j
    const int cbase = (bj << 7) + wc + fr;                    // + n*16
    const float cw = ((bi < 16) == (bj < 16)) ? 1.0f : 0.5f;
    const float* basep = pos_dots + (size_t)p * 8192;

    float ssum = 0.f;
    int cc = 0;
    if (bi == bj) {
      // diagonal tile: both halves together enumerate all ordered pairs once
#pragma unroll
      for (int m = 0; m < 2; m++)
#pragma unroll
        for (int n = 0; n < 4; n++) {
          f32x4 v = *(const f32x4*)(basep + (((m << 2) + n) << 10) + (t << 2));
          int c = cbase + (n << 4);
#pragma unroll
          for (int j = 0; j < 4; j++) {
            int r = rbase + (m << 4) + j;
            if (r != c) {               // excludes true diagonal
              float d = v[j];
              ssum += d;
              cc += (d > dec_ord(neg_max[r])) ? 1 : 0;
            }
          }
        }
    } else {
      float nmr[2][4], nmc[4];
#pragma unroll
      for (int m = 0; m < 2; m++)
#pragma unroll
        for (int j = 0; j < 4; j++) nmr[m][j] = dec_ord(neg_max[rbase + (m << 4) + j]);
#pragma unroll
      for (int n = 0; n < 4; n++) nmc[n] = dec_ord(neg_max[cbase + (n << 4)]);
#pragma unroll
      for (int m = 0; m < 2; m++)
#pragma unroll
        for (int n = 0; n < 4; n++) {
          f32x4 v = *(const f32x4*)(basep + (((m << 2) + n) << 10) + (t << 2));
#pragma unroll
          for (int j = 0; j < 4; j++) {
            float d = v[j];
            ssum += d;
            cc += ((d > nmr[m][j]) ? 1 : 0) + ((d > nmc[n]) ? 1 : 0);
          }
        }
      ssum *= 2.0f;   // both orientations
    }
    ssum *= cw;

#pragma unroll
    for (int o = 1; o < 64; o <<= 1) {
      ssum += __shfl_xor(ssum, o, 64);
      cc   += __shfl_xor(cc, o, 64);
    }
    if (lane == 0) { wsum[wave] = ssum; wcnt[wave] = cc; }
    __syncthreads();
    if (t == 0) {
      float S2 = 0.f; int C2 = 0;
      for (int w = 0; w < 4; w++) { S2 += wsum[w]; C2 += wcnt[w]; }
      atomicAdd(sumS, S2);
      atomicAdd(corr, (float)C2);
    }
  }

  // completion detection (block-uniform broadcast via shared)
  if (t == 0) {
    int my = -1;
    if (p < np2) { __threadfence(); my = atomicAdd(done, 1); }
    amLast = (my == np2 - 1) ? 1 : 0;
  }
  __syncthreads();
  if (!amLast) return;
  __threadfence();

  // finalize: loss = (sum_r W_r*log(neg_sum_r) - TEMP*sumS) / total_pos
  float aa = 0.f;
  for (int r = t; r < NT; r += 256) {
    int g = r >> 8;                     // 256-row group, 0..15
    float W = ov[g & 7] ? 383.f : 255.f;
    aa += W * __logf(neg_sum[r]);
  }
#pragma unroll
  for (int o = 1; o < 64; o <<= 1) aa += __shfl_xor(aa, o, 64);
  if (lane == 0) wsum[wave] = aa;
  __syncthreads();
  if (t == 0) {
    float sw = wsum[0] + wsum[1] + wsum[2] + wsum[3];
    float S = atomicAdd(sumS, 0.f);     // coherent read past L1
    float C = atomicAdd(corr, 0.f);
    float tp = 0.f;
    for (int g = 0; g < 16; g++) tp += 256.f * (255.f + 256.f * (ov[g & 7] ? 1.f : 0.f));
    out[0] = C / tp;
    out[1] = (sw - TEMPW * S) / tp;
  }
}

// ---- launch ----------------------------------------------------------------

extern "C" void kernel_launch(void* const* d_in, const int* in_sizes, int n_in,
                              void* d_out, int out_size, void* d_ws, size_t ws_size,
                              hipStream_t stream)
{
  const float* f1 = (const float*)d_in[0];
  const float* f2 = (const float*)d_in[1];
  const int*   ov = (const int*)d_in[2];

  char* ws = (char*)d_ws;
  ushort_t* bf       = (ushort_t*)ws;                                    // 4 MB
  float*    neg_sum  = (float*)(ws + (size_t)(4 << 20));                 // 16 KB
  unsigned* neg_max  = (unsigned*)(ws + (size_t)(4 << 20) + (16 << 10)); // 16 KB
  float*    sumS     = (float*)(ws + (size_t)(4 << 20) + (32 << 10));
  float*    corr     = sumS + 1;
  int*      cnts     = (int*)(sumS + 2);                                 // 3 ints
  int*      done     = cnts + 2;                                         // alias cnts[2]
  int*      neg_list = (int*)(ws + (size_t)(4 << 20) + (36 << 10));      // <=496
  int*      pos_list = (int*)(ws + (size_t)(4 << 20) + (40 << 10));      // <=80
  float*    pos_dots = (float*)(ws + (size_t)(4 << 20) + (64 << 10));    // 5.25 MB
  float*    out      = (float*)d_out;

  hipLaunchKernelGGL(prep_k, dim3(1024), dim3(256), 0, stream,
                     f1, f2, bf, neg_sum, neg_max, sumS, corr, cnts,
                     neg_list, pos_list, ov);
  hipLaunchKernelGGL(gram_k, dim3(1056), dim3(256), 0, stream,
                     bf, cnts, neg_list, pos_list, neg_sum, neg_max, pos_dots);
  hipLaunchKernelGGL(pos_fin_k, dim3(160), dim3(256), 0, stream,
                     pos_dots, cnts, pos_list, neg_max, neg_sum, ov,
                     sumS, corr, done, out);
}